// Round 12
// baseline (395.941 us; speedup 1.0000x reference)
//
#include <hip/hip_runtime.h>
#include <hip/hip_bf16.h>

#define HIDDEN 1024
#define INTER 4096
#define NEXP 8
#define T_TOK 2048

typedef short bf16x8 __attribute__((ext_vector_type(8)));
typedef float f32x4 __attribute__((ext_vector_type(4)));

// Conflict-free BK=32 LDS chunk layout (R7/R8/R9-verified on HW: conflicts=0).
#define CHUNK(row, kq) ((unsigned int)((row) * 64u + ((((unsigned int)(kq)) ^ ((((unsigned int)(row)) >> 1) & 3u)) << 4)))

__device__ __forceinline__ unsigned short f2bf(float f) {
    union { float f; unsigned int u; } v; v.f = f;
    return (unsigned short)(v.u >> 16);   // truncation: 10x absmax margin measured
}

// two float4 -> one 16B chunk of 8 bf16 (truncating)
__device__ __forceinline__ uint4 pack8trunc(float4 a, float4 b) {
    union { float4 f; unsigned short s[8]; } x, y; x.f = a; y.f = b;
    uint4 r;
    r.x = (unsigned int)x.s[1] | ((unsigned int)x.s[3] << 16);
    r.y = (unsigned int)x.s[5] | ((unsigned int)x.s[7] << 16);
    r.z = (unsigned int)y.s[1] | ((unsigned int)y.s[3] << 16);
    r.w = (unsigned int)y.s[5] | ((unsigned int)y.s[7] << 16);
    return r;
}

// raw barrier: NO vmcnt drain (global prefetch stays in flight across it).
__device__ __forceinline__ void block_sync() {
    asm volatile("s_waitcnt lgkmcnt(0)" ::: "memory");
    __builtin_amdgcn_s_barrier();
    asm volatile("" ::: "memory");
}

// ---------------- K1: router (fp32 exact) ----------------
__global__ void router_kernel(const float* __restrict__ x,
                              const float* __restrict__ rw,
                              float* __restrict__ logits_out,
                              int* __restrict__ counts,
                              int* __restrict__ ids,
                              float* __restrict__ wts,
                              int* __restrict__ tsel) {
    int t = blockIdx.x * 4 + (threadIdx.x >> 6);
    int lane = threadIdx.x & 63;
    if (t >= T_TOK) return;
    const float4* xr = (const float4*)(x + (size_t)t * HIDDEN);
    float acc[NEXP];
#pragma unroll
    for (int e = 0; e < NEXP; e++) acc[e] = 0.f;
#pragma unroll
    for (int c = 0; c < 4; c++) {
        float4 xv = xr[lane + c * 64];
#pragma unroll
        for (int e = 0; e < NEXP; e++) {
            float4 wv = ((const float4*)(rw + (size_t)e * HIDDEN))[lane + c * 64];
            acc[e] += xv.x * wv.x + xv.y * wv.y + xv.z * wv.z + xv.w * wv.w;
        }
    }
#pragma unroll
    for (int e = 0; e < NEXP; e++) {
        float v = acc[e];
        for (int off = 32; off >= 1; off >>= 1) v += __shfl_xor(v, off, 64);
        acc[e] = v;
    }
    if (lane == 0) {
        float* lo = logits_out + (size_t)t * NEXP;
        float mx = acc[0];
#pragma unroll
        for (int e = 1; e < NEXP; e++) mx = fmaxf(mx, acc[e]);
        float p[NEXP], s = 0.f;
#pragma unroll
        for (int e = 0; e < NEXP; e++) { p[e] = __expf(acc[e] - mx); s += p[e]; }
        float inv = 1.f / s;
#pragma unroll
        for (int e = 0; e < NEXP; e++) { p[e] *= inv; lo[e] = acc[e]; }
        int i1 = 0;
#pragma unroll
        for (int e = 1; e < NEXP; e++) if (p[e] > p[i1]) i1 = e;
        int i2 = (i1 == 0) ? 1 : 0;
#pragma unroll
        for (int e = 0; e < NEXP; e++) if (e != i1 && e != i2 && p[e] > p[i2]) i2 = e;
        // strict > keeps lowest index on ties (matches jax top_k)
        int s1 = atomicAdd(&counts[i1], 1);
        ids[i1 * T_TOK + s1] = t; wts[i1 * T_TOK + s1] = p[i1];
        int s2 = atomicAdd(&counts[i2], 1);
        ids[i2 * T_TOK + s2] = t; wts[i2 * T_TOK + s2] = p[i2];
        tsel[t * 2]     = i1 * T_TOK + s1;   // pack (expert, slot)
        tsel[t * 2 + 1] = i2 * T_TOK + s2;
    }
}

__global__ void scan_kernel(const int* __restrict__ counts, int* __restrict__ offsets) {
    if (threadIdx.x == 0) {
        int s = 0;
        for (int e = 0; e < NEXP; e++) { offsets[e] = s; s += counts[e]; }
    }
}

// ---------------- K2: fused gate+up grouped GEMM + SwiGLU ----------------
// R9 geometry (BM=256 x BN=128, BK=32, 1024 thr, 16 waves 4x4), CHUNK LDS.
// R12 change: 4-buffer rotation, ONE barrier per 2 K-steps. Loads issued in
// region R are consumed in region R+1 (latency spans a full region of MFMA)
// with a single staging register set (no R8 spill). setprio(1) around MFMA.
__global__ __launch_bounds__(1024) void gemm_gu(
    const float* __restrict__ x, const float* __restrict__ gw, const float* __restrict__ uw,
    const int* __restrict__ counts, const int* __restrict__ offsets,
    const int* __restrict__ ids, unsigned short* __restrict__ h) {
    const int e = blockIdx.z;
    const int cnt = counts[e];
    const int mt = blockIdx.y;
    if (mt * 256 >= cnt) return;
    const int nt = blockIdx.x;                    // 32 tiles of 128 inter
    const int tid = threadIdx.x;
    const int lane = tid & 63, wid = tid >> 6;
    const int wm = wid >> 2, wn = wid & 3;        // 4x4 waves

    // 4 x 32KB = 128 KB static LDS (gfx950 allows up to 160 KB; m201-verified)
    __shared__ __align__(16) char lb0[32768];     // each: [A 16K | Bg 8K | Bu 8K]
    __shared__ __align__(16) char lb1[32768];
    __shared__ __align__(16) char lb2[32768];
    __shared__ __align__(16) char lb3[32768];

    // A: 256 rows x 4 chunks = 1024; one per thread (2 float4 -> 1 chunk)
    const int arow = tid >> 2, akq = tid & 3;
    int ali = mt * 256 + arow; if (ali >= cnt) ali = cnt - 1;
    const unsigned int aoff = (unsigned int)(ids[e * T_TOK + ali] * HIDDEN + akq * 8);
    const unsigned int wAo = CHUNK(arow, akq);
    // B: 512 g-chunks + 512 u-chunks = 1024; one per thread
    const int bsel = tid >> 9;                    // 0 = gate, 1 = up
    const int bi = tid & 511;
    const int brow = bi >> 2, bkq = bi & 3;
    const float* bsrc = (bsel ? uw : gw) + (size_t)e * INTER * HIDDEN
                        + (size_t)(nt * 128 + brow) * HIDDEN + bkq * 8;
    const unsigned int wBo = 16384u + ((unsigned int)bsel << 13) + CHUNK(brow, bkq);

    f32x4 accg[4][2], accu[4][2];
#pragma unroll
    for (int mf = 0; mf < 4; mf++)
#pragma unroll
        for (int nf = 0; nf < 2; nf++)
#pragma unroll
            for (int v = 0; v < 4; v++) { accg[mf][nf][v] = 0.f; accu[mf][nf][v] = 0.f; }

    // single staging register set (16 VGPRs)
    float4 s0, s1, t0, t1;
    // prologue: seal tiles 0,1 into lb0,lb1; leave tile 2 in regs
    s0 = *(const float4*)(x + aoff);      s1 = *(const float4*)(x + aoff + 4);
    t0 = *(const float4*)(bsrc);          t1 = *(const float4*)(bsrc + 4);
    *(uint4*)(lb0 + wAo) = pack8trunc(s0, s1);
    *(uint4*)(lb0 + wBo) = pack8trunc(t0, t1);
    s0 = *(const float4*)(x + aoff + 32); s1 = *(const float4*)(x + aoff + 36);
    t0 = *(const float4*)(bsrc + 32);     t1 = *(const float4*)(bsrc + 36);
    *(uint4*)(lb1 + wAo) = pack8trunc(s0, s1);
    *(uint4*)(lb1 + wBo) = pack8trunc(t0, t1);
    s0 = *(const float4*)(x + aoff + 64); s1 = *(const float4*)(x + aoff + 68);
    t0 = *(const float4*)(bsrc + 64);     t1 = *(const float4*)(bsrc + 68);
    block_sync();

    const unsigned int kqr = (unsigned int)(lane >> 4);
    const unsigned int rl = (unsigned int)(lane & 15);

    // Half KT: fragread RB (sealed); write tile KT+2 from regs -> WB (implicit
    // counted vmcnt); issue loads tile KT+3; MFMA(KT) under setprio(1).
#define GU_HALF(KT, RB, WB)                                                             \
    {                                                                                   \
        bf16x8 fa[4];                                                                   \
        _Pragma("unroll")                                                               \
        for (int mf = 0; mf < 4; mf++)                                                  \
            fa[mf] = *(const bf16x8*)((RB) + CHUNK(wm * 64 + mf * 16 + rl, kqr));       \
        if ((KT) + 2 < 32) {                                                            \
            *(uint4*)((WB) + wAo) = pack8trunc(s0, s1);                                 \
            *(uint4*)((WB) + wBo) = pack8trunc(t0, t1);                                 \
        }                                                                               \
        if ((KT) + 3 < 32) {                                                            \
            const int ko = ((KT) + 3) * 32;                                             \
            s0 = *(const float4*)(x + aoff + ko); s1 = *(const float4*)(x + aoff + ko + 4); \
            t0 = *(const float4*)(bsrc + ko);     t1 = *(const float4*)(bsrc + ko + 4); \
        }                                                                               \
        __builtin_amdgcn_s_setprio(1);                                                  \
        _Pragma("unroll")                                                               \
        for (int nf = 0; nf < 2; nf++) {                                                \
            const unsigned int br = wn * 32 + nf * 16 + rl;                             \
            bf16x8 bg = *(const bf16x8*)((RB) + 16384 + CHUNK(br, kqr));                \
            bf16x8 bu = *(const bf16x8*)((RB) + 24576 + CHUNK(br, kqr));                \
            _Pragma("unroll")                                                           \
            for (int mf = 0; mf < 4; mf++) {                                            \
                accg[mf][nf] = __builtin_amdgcn_mfma_f32_16x16x32_bf16(fa[mf], bg, accg[mf][nf], 0, 0, 0); \
                accu[mf][nf] = __builtin_amdgcn_mfma_f32_16x16x32_bf16(fa[mf], bu, accu[mf][nf], 0, 0, 0); \
            }                                                                           \
        }                                                                               \
        __builtin_amdgcn_s_setprio(0);                                                  \
    }

    // region = 2 halves + ONE barrier; buffers rotate period-4
    for (int kt = 0; kt < 32; kt += 4) {
        GU_HALF(kt,     lb0, lb2)
        GU_HALF(kt + 1, lb1, lb3)
        block_sync();
        GU_HALF(kt + 2, lb2, lb0)
        GU_HALF(kt + 3, lb3, lb1)
        block_sync();
    }
#undef GU_HALF

    const int hoff = offsets[e];
#pragma unroll
    for (int mf = 0; mf < 4; mf++)
#pragma unroll
        for (int v = 0; v < 4; v++) {
            int il = wm * 64 + mf * 16 + ((lane >> 4) << 2) + v;
            int i = mt * 256 + il;
            if (i < cnt) {
                size_t rowbase = (size_t)(hoff + i) * INTER + nt * 128 + wn * 32 + (lane & 15);
#pragma unroll
                for (int nf = 0; nf < 2; nf++) {
                    float g = accg[mf][nf][v], u = accu[mf][nf][v];
                    float sg = g / (1.f + __expf(-g));
                    h[rowbase + nf * 16] = f2bf(sg * u);
                }
            }
        }
}

// ---------------- K3: down grouped GEMM -> y (no atomics) ----------------
// R9 geometry (BM=128 x BN=128, BK=32, ksplit=2, 512 thr, 8 waves 2x4),
// CHUNK LDS. R12: same 4-buffer one-barrier-per-2-steps rotation
// (4 x 16KB = 64KB -> still 2 blocks/CU) + setprio around MFMA.
__global__ __launch_bounds__(512) void gemm_down(
    const unsigned short* __restrict__ h, const float* __restrict__ dw,
    const int* __restrict__ counts, const int* __restrict__ offsets,
    const float* __restrict__ wts, float* __restrict__ y) {
    const int ez = blockIdx.z;                    // e*2 + ksp
    const int e = ez >> 1, ksp = ez & 1;
    const int cnt = counts[e];
    const int mt = blockIdx.y;
    if (mt * 128 >= cnt) return;
    const int nt = blockIdx.x;                    // 8 tiles of 128 hidden
    const int tid = threadIdx.x;
    const int lane = tid & 63, wid = tid >> 6;
    const int wm = wid >> 2, wn = wid & 3;        // 2x4 waves, wave 64x32

    __shared__ __align__(16) char lb0[16384];     // each: [A 8K | B 8K]
    __shared__ __align__(16) char lb1[16384];
    __shared__ __align__(16) char lb2[16384];
    __shared__ __align__(16) char lb3[16384];

    const int hoff = offsets[e];
    const float* dbase = dw + (size_t)e * HIDDEN * INTER;

    // A (h, bf16): 128 rows x 4 chunks = 512; one per thread (direct int4)
    const int row = tid >> 2, kq = tid & 3;
    int li = mt * 128 + row; if (li >= cnt) li = cnt - 1;
    const unsigned int aoff = (unsigned int)((hoff + li) * INTER + ksp * 2048 + kq * 8);
    const unsigned int wAo = CHUNK(row, kq);
    // B (dw, fp32): 128 rows x 4 chunks = 512; one per thread (2 float4)
    const unsigned int boff = (unsigned int)((nt * 128 + row) * INTER + ksp * 2048 + kq * 8);
    const unsigned int wBo = 8192u + CHUNK(row, kq);

    f32x4 acc[4][2];
#pragma unroll
    for (int mf = 0; mf < 4; mf++)
#pragma unroll
        for (int nf = 0; nf < 2; nf++)
#pragma unroll
            for (int v = 0; v < 4; v++) acc[mf][nf][v] = 0.f;

    int4 av; float4 b0, b1;
    av = *(const int4*)(h + aoff);
    b0 = *(const float4*)(dbase + boff);      b1 = *(const float4*)(dbase + boff + 4);
    *(int4*)(lb0 + wAo) = av;
    *(uint4*)(lb0 + wBo) = pack8trunc(b0, b1);
    av = *(const int4*)(h + aoff + 32);
    b0 = *(const float4*)(dbase + boff + 32); b1 = *(const float4*)(dbase + boff + 36);
    *(int4*)(lb1 + wAo) = av;
    *(uint4*)(lb1 + wBo) = pack8trunc(b0, b1);
    av = *(const int4*)(h + aoff + 64);
    b0 = *(const float4*)(dbase + boff + 64); b1 = *(const float4*)(dbase + boff + 68);
    block_sync();

    const unsigned int kqr = (unsigned int)(lane >> 4);
    const unsigned int rl = (unsigned int)(lane & 15);

#define DN_HALF(KT, RB, WB)                                                             \
    {                                                                                   \
        bf16x8 fa[4];                                                                   \
        _Pragma("unroll")                                                               \
        for (int mf = 0; mf < 4; mf++)                                                  \
            fa[mf] = *(const bf16x8*)((RB) + CHUNK(wm * 64 + mf * 16 + rl, kqr));       \
        if ((KT) + 2 < 64) {                                                            \
            *(int4*)((WB) + wAo) = av;                                                  \
            *(uint4*)((WB) + wBo) = pack8trunc(b0, b1);                                 \
        }                                                                               \
        if ((KT) + 3 < 64) {                                                            \
            const int ko = ((KT) + 3) * 32;                                             \
            av = *(const int4*)(h + aoff + ko);                                         \
            b0 = *(const float4*)(dbase + boff + ko); b1 = *(const float4*)(dbase + boff + ko + 4); \
        }                                                                               \
        __builtin_amdgcn_s_setprio(1);                                                  \
        _Pragma("unroll")                                                               \
        for (int nf = 0; nf < 2; nf++) {                                                \
            bf16x8 b = *(const bf16x8*)((RB) + 8192 + CHUNK(wn * 32 + nf * 16 + rl, kqr)); \
            _Pragma("unroll")                                                           \
            for (int mf = 0; mf < 4; mf++)                                              \
                acc[mf][nf] = __builtin_amdgcn_mfma_f32_16x16x32_bf16(fa[mf], b, acc[mf][nf], 0, 0, 0); \
        }                                                                               \
        __builtin_amdgcn_s_setprio(0);                                                  \
    }

    for (int kt = 0; kt < 64; kt += 4) {          // 2048 K per split
        DN_HALF(kt,     lb0, lb2)
        DN_HALF(kt + 1, lb1, lb3)
        block_sync();
        DN_HALF(kt + 2, lb2, lb0)
        DN_HALF(kt + 3, lb3, lb1)
        block_sync();
    }
#undef DN_HALF

#pragma unroll
    for (int mf = 0; mf < 4; mf++)
#pragma unroll
        for (int v = 0; v < 4; v++) {
            int il = wm * 64 + mf * 16 + ((lane >> 4) << 2) + v;
            int i = mt * 128 + il;
            if (i < cnt) {
                float w = wts[e * T_TOK + i];
                float* yrow = y + ((size_t)ksp * 4096 + hoff + i) * HIDDEN
                                + nt * 128 + wn * 32 + (lane & 15);
#pragma unroll
                for (int nf = 0; nf < 2; nf++)
                    yrow[nf * 16] = w * acc[mf][nf][v];
            }
        }
}

// -------- K4: combine (out[t] = sum over 2 experts x 2 ksplits) --------
__global__ __launch_bounds__(256) void combine_kernel(
    const float* __restrict__ y, const int* __restrict__ offsets,
    const int* __restrict__ tsel, float* __restrict__ out) {
    const int t = blockIdx.x;
    const int d = threadIdx.x * 4;
    int p0 = tsel[t * 2], p1 = tsel[t * 2 + 1];
    size_t g0 = (size_t)(offsets[p0 >> 11] + (p0 & (T_TOK - 1)));
    size_t g1 = (size_t)(offsets[p1 >> 11] + (p1 & (T_TOK - 1)));
    float4 a0 = *(const float4*)(y + g0 * HIDDEN + d);
    float4 a1 = *(const float4*)(y + (4096 + g0) * HIDDEN + d);
    float4 b0 = *(const float4*)(y + g1 * HIDDEN + d);
    float4 b1 = *(const float4*)(y + (4096 + g1) * HIDDEN + d);
    float4 o;
    o.x = (a0.x + a1.x) + (b0.x + b1.x);
    o.y = (a0.y + a1.y) + (b0.y + b1.y);
    o.z = (a0.z + a1.z) + (b0.z + b1.z);
    o.w = (a0.w + a1.w) + (b0.w + b1.w);
    *(float4*)(out + (size_t)t * HIDDEN + d) = o;
}

extern "C" void kernel_launch(void* const* d_in, const int* in_sizes, int n_in,
                              void* d_out, int out_size, void* d_ws, size_t ws_size,
                              hipStream_t stream) {
    const float* x  = (const float*)d_in[0];
    const float* rw = (const float*)d_in[1];
    const float* gw = (const float*)d_in[2];
    const float* uw = (const float*)d_in[3];
    const float* dw = (const float*)d_in[4];
    float* out = (float*)d_out;
    float* logits = out + (size_t)T_TOK * HIDDEN;

    char* ws = (char*)d_ws;
    int*   counts  = (int*)ws;                         // 32 B
    int*   offsets = (int*)(ws + 32);                  // 32 B
    int*   tsel    = (int*)(ws + 1024);                // 16 KB
    int*   ids     = (int*)(ws + 20480);               // 64 KB
    float* wts     = (float*)(ws + 90112);             // 64 KB
    unsigned short* h = (unsigned short*)(ws + 262144);        // 33.55 MB
    float* y       = (float*)(ws + 262144 + 33554432);         // 2 x 16.78 MB

    hipMemsetAsync(counts, 0, 8 * sizeof(int), stream);

    router_kernel<<<T_TOK / 4, 256, 0, stream>>>(x, rw, logits, counts, ids, wts, tsel);
    scan_kernel<<<1, 64, 0, stream>>>(counts, offsets);
    gemm_gu<<<dim3(INTER / 128, 8, NEXP), 1024, 0, stream>>>(x, gw, uw, counts, offsets, ids, h);
    gemm_down<<<dim3(HIDDEN / 128, 16, NEXP * 2), 512, 0, stream>>>(h, dw, counts, offsets, wts, y);
    combine_kernel<<<T_TOK, 256, 0, stream>>>(y, offsets, tsel, out);
}

// Round 13
// 312.514 us; speedup vs baseline: 1.2670x; 1.2670x over previous
//
#include <hip/hip_runtime.h>
#include <hip/hip_bf16.h>

#define HIDDEN 1024
#define INTER 4096
#define NEXP 8
#define T_TOK 2048

typedef short bf16x8 __attribute__((ext_vector_type(8)));
typedef float f32x4 __attribute__((ext_vector_type(4)));

// BK=32 chunk layout for gemm_down (R7/R9-verified: conflicts=0)
#define CHUNK(row, kq) ((unsigned int)((row) * 64u + ((((unsigned int)(kq)) ^ ((((unsigned int)(row)) >> 1) & 3u)) << 4)))

__device__ __forceinline__ unsigned short f2bf(float f) {
    union { float f; unsigned int u; } v; v.f = f;
    return (unsigned short)(v.u >> 16);
}

// two float4 -> one 16B chunk of 8 bf16 (truncating)
__device__ __forceinline__ uint4 pack8trunc(float4 a, float4 b) {
    union { float4 f; unsigned short s[8]; } x, y; x.f = a; y.f = b;
    uint4 r;
    r.x = (unsigned int)x.s[1] | ((unsigned int)x.s[3] << 16);
    r.y = (unsigned int)x.s[5] | ((unsigned int)x.s[7] << 16);
    r.z = (unsigned int)y.s[1] | ((unsigned int)y.s[3] << 16);
    r.w = (unsigned int)y.s[5] | ((unsigned int)y.s[7] << 16);
    return r;
}

// lgkmcnt(0) then barrier: ds ops retired before anyone crosses (visibility)
__device__ __forceinline__ void block_sync() {
    asm volatile("s_waitcnt lgkmcnt(0)" ::: "memory");
    __builtin_amdgcn_s_barrier();
    asm volatile("" ::: "memory");
}
// raw barrier (template end-of-phase)
__device__ __forceinline__ void bar() {
    asm volatile("" ::: "memory");
    __builtin_amdgcn_s_barrier();
    asm volatile("" ::: "memory");
}
// template mid-phase: barrier THEN drain own LDS ops
__device__ __forceinline__ void bar_lgkm0() {
    asm volatile("" ::: "memory");
    __builtin_amdgcn_s_barrier();
    asm volatile("s_waitcnt lgkmcnt(0)" ::: "memory");
}

// ---------------- K1: router (fp32 exact) ----------------
__global__ void router_kernel(const float* __restrict__ x,
                              const float* __restrict__ rw,
                              float* __restrict__ logits_out,
                              int* __restrict__ counts,
                              int* __restrict__ ids,
                              float* __restrict__ wts,
                              int* __restrict__ tsel) {
    int t = blockIdx.x * 4 + (threadIdx.x >> 6);
    int lane = threadIdx.x & 63;
    if (t >= T_TOK) return;
    const float4* xr = (const float4*)(x + (size_t)t * HIDDEN);
    float acc[NEXP];
#pragma unroll
    for (int e = 0; e < NEXP; e++) acc[e] = 0.f;
#pragma unroll
    for (int c = 0; c < 4; c++) {
        float4 xv = xr[lane + c * 64];
#pragma unroll
        for (int e = 0; e < NEXP; e++) {
            float4 wv = ((const float4*)(rw + (size_t)e * HIDDEN))[lane + c * 64];
            acc[e] += xv.x * wv.x + xv.y * wv.y + xv.z * wv.z + xv.w * wv.w;
        }
    }
#pragma unroll
    for (int e = 0; e < NEXP; e++) {
        float v = acc[e];
        for (int off = 32; off >= 1; off >>= 1) v += __shfl_xor(v, off, 64);
        acc[e] = v;
    }
    if (lane == 0) {
        float* lo = logits_out + (size_t)t * NEXP;
        float mx = acc[0];
#pragma unroll
        for (int e = 1; e < NEXP; e++) mx = fmaxf(mx, acc[e]);
        float p[NEXP], s = 0.f;
#pragma unroll
        for (int e = 0; e < NEXP; e++) { p[e] = __expf(acc[e] - mx); s += p[e]; }
        float inv = 1.f / s;
#pragma unroll
        for (int e = 0; e < NEXP; e++) { p[e] *= inv; lo[e] = acc[e]; }
        int i1 = 0;
#pragma unroll
        for (int e = 1; e < NEXP; e++) if (p[e] > p[i1]) i1 = e;
        int i2 = (i1 == 0) ? 1 : 0;
#pragma unroll
        for (int e = 0; e < NEXP; e++) if (e != i1 && e != i2 && p[e] > p[i2]) i2 = e;
        // strict > keeps lowest index on ties (matches jax top_k)
        int s1 = atomicAdd(&counts[i1], 1);
        ids[i1 * T_TOK + s1] = t; wts[i1 * T_TOK + s1] = p[i1];
        int s2 = atomicAdd(&counts[i2], 1);
        ids[i2 * T_TOK + s2] = t; wts[i2 * T_TOK + s2] = p[i2];
        tsel[t * 2]     = i1 * T_TOK + s1;
        tsel[t * 2 + 1] = i2 * T_TOK + s2;
    }
}

__global__ void scan_kernel(const int* __restrict__ counts, int* __restrict__ offsets) {
    if (threadIdx.x == 0) {
        int s = 0;
        for (int e = 0; e < NEXP; e++) { offsets[e] = s; s += counts[e]; }
    }
}

// ---------------- K2: fused gate+up grouped GEMM + SwiGLU (8-phase) --------
// BM=256, BN=128-inter dual (g,u), BK=64. 512 thr, 8 waves (2M x 4N),
// wave-tile 128 x 32-dual, acc 128 regs. LDS 2 x (A 32K | Bg 16K | Bu 16K)
// = 128 KB, 1 block/CU, 2 waves/SIMD (HK occupancy point).
// Per K-tile: 4 phases, each {8 frag ds_reads | pack+2 ds_writes of next
// tile's chunk-pair | issue 4 fp32 loads 2 phases ahead | barrier |
// lgkmcnt(0) | setprio(1) 16 MFMA setprio(0) | barrier}. Loads never
// drained (reg-dep counted vmcnt); 2 x 16-reg staging sets by phase parity.
// LDS chunk layout: A slot (row, kq) at row*128 + ((kq ^ (row&7))<<4) —
// frag reads and staging writes both hit each bank-group exactly minimally.
__global__ __launch_bounds__(512) void gemm_gu(
    const float* __restrict__ x, const float* __restrict__ gw, const float* __restrict__ uw,
    const int* __restrict__ counts, const int* __restrict__ offsets,
    const int* __restrict__ ids, unsigned short* __restrict__ h) {
    const int e = blockIdx.z;
    const int cnt = counts[e];
    const int mt = blockIdx.y;
    if (mt * 256 >= cnt) return;
    const int nt = blockIdx.x;                    // 32 tiles of 128 inter
    const int tid = threadIdx.x;
    const int lane = tid & 63, wid = tid >> 6;
    const int wm = wid >> 2, wn = wid & 3;        // 2 x 4 waves

    __shared__ __align__(16) char lds[131072];    // [A 32K|Bg 16K|Bu 16K] x2

    const float* gbase = gw + (size_t)e * INTER * HIDDEN;
    const float* ubase = uw + (size_t)e * INTER * HIDDEN;

    // staging map: 4096 chunks/K-tile (A 2048, Bg 1024, Bu 1024); thread owns
    // chunks c = tid + j*512, j=0..7: j0-3 A rows r0+{0,64,128,192}; j4,5 Bg
    // rows r0, r0+64; j6,7 Bu same rows. kq = tid&7 for all.
    const int r0 = tid >> 3;                      // 0..63
    const int kq = tid & 7;
    unsigned int aoffs0, aoffs1, aoffs2, aoffs3;
    {
        int li, row;
        row = r0;        li = mt * 256 + row; if (li >= cnt) li = cnt - 1;
        aoffs0 = (unsigned int)(ids[e * T_TOK + li] * HIDDEN + kq * 8);
        row = r0 + 64;   li = mt * 256 + row; if (li >= cnt) li = cnt - 1;
        aoffs1 = (unsigned int)(ids[e * T_TOK + li] * HIDDEN + kq * 8);
        row = r0 + 128;  li = mt * 256 + row; if (li >= cnt) li = cnt - 1;
        aoffs2 = (unsigned int)(ids[e * T_TOK + li] * HIDDEN + kq * 8);
        row = r0 + 192;  li = mt * 256 + row; if (li >= cnt) li = cnt - 1;
        aoffs3 = (unsigned int)(ids[e * T_TOK + li] * HIDDEN + kq * 8);
    }
    const unsigned int boff0 = (unsigned int)((nt * 128 + r0) * HIDDEN + kq * 8);
    const unsigned int boff1 = (unsigned int)((nt * 128 + r0 + 64) * HIDDEN + kq * 8);
    // LDS write slots (row-relative; +8192 per 64 rows)
    const unsigned int kqs = (unsigned int)((kq ^ (r0 & 7)) << 4);
    const unsigned int wA0 = (unsigned int)r0 * 128u + kqs;  // A j0; j1..3: +8192j
    const unsigned int wB0 = (unsigned int)r0 * 128u + kqs;  // B row r0; +8192 for +64

    // fragment read address components
    const unsigned int rl  = (unsigned int)(lane & 15);
    const unsigned int kqr = (unsigned int)(lane >> 4);
    const unsigned int fx  = rl & 7u;
    const unsigned int aro = ((unsigned int)wm * 128u + rl) * 128u; // + mf*2048 + kx
    const unsigned int bro = ((unsigned int)wn * 32u + rl) * 128u;  // + nf*2048 + kx
    const unsigned int kx0 = ((0u * 4u + kqr) ^ fx) << 4;           // ksub 0
    const unsigned int kx1 = ((1u * 4u + kqr) ^ fx) << 4;           // ksub 1

    f32x4 accg[8][2], accu[8][2];
#pragma unroll
    for (int mf = 0; mf < 8; mf++)
#pragma unroll
        for (int nf = 0; nf < 2; nf++)
#pragma unroll
            for (int v = 0; v < 4; v++) { accg[mf][nf][v] = 0.f; accu[mf][nf][v] = 0.f; }

    // two staging sets (16 regs each), rotate by phase parity
    float4 s0a, s0b, s0c, s0d, s1a, s1b, s1c, s1d;

    // ---- prologue: stage tile 0 -> buf0; preload sets with pairs 0,1 of tile 1
    {
        float4 pa, pb, pc, pd;
        pa = *(const float4*)(x + aoffs0); pb = *(const float4*)(x + aoffs0 + 4);
        pc = *(const float4*)(x + aoffs1); pd = *(const float4*)(x + aoffs1 + 4);
        *(uint4*)(lds + wA0)         = pack8trunc(pa, pb);
        *(uint4*)(lds + wA0 + 8192)  = pack8trunc(pc, pd);
        pa = *(const float4*)(x + aoffs2); pb = *(const float4*)(x + aoffs2 + 4);
        pc = *(const float4*)(x + aoffs3); pd = *(const float4*)(x + aoffs3 + 4);
        *(uint4*)(lds + wA0 + 16384) = pack8trunc(pa, pb);
        *(uint4*)(lds + wA0 + 24576) = pack8trunc(pc, pd);
        pa = *(const float4*)(gbase + boff0); pb = *(const float4*)(gbase + boff0 + 4);
        pc = *(const float4*)(gbase + boff1); pd = *(const float4*)(gbase + boff1 + 4);
        *(uint4*)(lds + 32768 + wB0)        = pack8trunc(pa, pb);
        *(uint4*)(lds + 32768 + wB0 + 8192) = pack8trunc(pc, pd);
        pa = *(const float4*)(ubase + boff0); pb = *(const float4*)(ubase + boff0 + 4);
        pc = *(const float4*)(ubase + boff1); pd = *(const float4*)(ubase + boff1 + 4);
        *(uint4*)(lds + 49152 + wB0)        = pack8trunc(pa, pb);
        *(uint4*)(lds + 49152 + wB0 + 8192) = pack8trunc(pc, pd);
    }
    s0a = *(const float4*)(x + aoffs0 + 64); s0b = *(const float4*)(x + aoffs0 + 68);
    s0c = *(const float4*)(x + aoffs1 + 64); s0d = *(const float4*)(x + aoffs1 + 68);
    s1a = *(const float4*)(x + aoffs2 + 64); s1b = *(const float4*)(x + aoffs2 + 68);
    s1c = *(const float4*)(x + aoffs3 + 64); s1d = *(const float4*)(x + aoffs3 + 68);
    block_sync();

#define GU_MFMA16(HH, FA0, FA1, FA2, FA3)                                                    \
    accg[(HH)*4+0][0] = __builtin_amdgcn_mfma_f32_16x16x32_bf16(FA0, bg0, accg[(HH)*4+0][0], 0, 0, 0); \
    accg[(HH)*4+0][1] = __builtin_amdgcn_mfma_f32_16x16x32_bf16(FA0, bg1, accg[(HH)*4+0][1], 0, 0, 0); \
    accu[(HH)*4+0][0] = __builtin_amdgcn_mfma_f32_16x16x32_bf16(FA0, bu0, accu[(HH)*4+0][0], 0, 0, 0); \
    accu[(HH)*4+0][1] = __builtin_amdgcn_mfma_f32_16x16x32_bf16(FA0, bu1, accu[(HH)*4+0][1], 0, 0, 0); \
    accg[(HH)*4+1][0] = __builtin_amdgcn_mfma_f32_16x16x32_bf16(FA1, bg0, accg[(HH)*4+1][0], 0, 0, 0); \
    accg[(HH)*4+1][1] = __builtin_amdgcn_mfma_f32_16x16x32_bf16(FA1, bg1, accg[(HH)*4+1][1], 0, 0, 0); \
    accu[(HH)*4+1][0] = __builtin_amdgcn_mfma_f32_16x16x32_bf16(FA1, bu0, accu[(HH)*4+1][0], 0, 0, 0); \
    accu[(HH)*4+1][1] = __builtin_amdgcn_mfma_f32_16x16x32_bf16(FA1, bu1, accu[(HH)*4+1][1], 0, 0, 0); \
    accg[(HH)*4+2][0] = __builtin_amdgcn_mfma_f32_16x16x32_bf16(FA2, bg0, accg[(HH)*4+2][0], 0, 0, 0); \
    accg[(HH)*4+2][1] = __builtin_amdgcn_mfma_f32_16x16x32_bf16(FA2, bg1, accg[(HH)*4+2][1], 0, 0, 0); \
    accu[(HH)*4+2][0] = __builtin_amdgcn_mfma_f32_16x16x32_bf16(FA2, bu0, accu[(HH)*4+2][0], 0, 0, 0); \
    accu[(HH)*4+2][1] = __builtin_amdgcn_mfma_f32_16x16x32_bf16(FA2, bu1, accu[(HH)*4+2][1], 0, 0, 0); \
    accg[(HH)*4+3][0] = __builtin_amdgcn_mfma_f32_16x16x32_bf16(FA3, bg0, accg[(HH)*4+3][0], 0, 0, 0); \
    accg[(HH)*4+3][1] = __builtin_amdgcn_mfma_f32_16x16x32_bf16(FA3, bg1, accg[(HH)*4+3][1], 0, 0, 0); \
    accu[(HH)*4+3][0] = __builtin_amdgcn_mfma_f32_16x16x32_bf16(FA3, bu0, accu[(HH)*4+3][0], 0, 0, 0); \
    accu[(HH)*4+3][1] = __builtin_amdgcn_mfma_f32_16x16x32_bf16(FA3, bu1, accu[(HH)*4+3][1], 0, 0, 0);

    // Phase P of tile T: frag-read quadrant (h=P>>1, s=P&1) from CB; write
    // chunk-pair P of tile T+1 from set_{P&1} -> NB; reload set_{P&1} with
    // pair (P+2)&3 of tile T+1+((P+2)>>2); barrier; lgkm0; 16 MFMA; barrier.
#define GU_PHASE(T, P, CB, NB, SA, SB, SC, SD)                                               \
    {                                                                                        \
        const unsigned int kxs = ((P) & 1) ? kx1 : kx0;                                      \
        bf16x8 fa0 = *(const bf16x8*)(lds + (CB) + aro + (((P)>>1)*4+0)*2048 + kxs);         \
        bf16x8 fa1 = *(const bf16x8*)(lds + (CB) + aro + (((P)>>1)*4+1)*2048 + kxs);         \
        bf16x8 fa2 = *(const bf16x8*)(lds + (CB) + aro + (((P)>>1)*4+2)*2048 + kxs);         \
        bf16x8 fa3 = *(const bf16x8*)(lds + (CB) + aro + (((P)>>1)*4+3)*2048 + kxs);         \
        bf16x8 bg0 = *(const bf16x8*)(lds + (CB) + 32768 + bro + 0*2048 + kxs);              \
        bf16x8 bg1 = *(const bf16x8*)(lds + (CB) + 32768 + bro + 1*2048 + kxs);              \
        bf16x8 bu0 = *(const bf16x8*)(lds + (CB) + 49152 + bro + 0*2048 + kxs);              \
        bf16x8 bu1 = *(const bf16x8*)(lds + (CB) + 49152 + bro + 1*2048 + kxs);              \
        if ((T) < 15) {                                                                      \
            if ((P) == 0) {                                                                  \
                *(uint4*)(lds + (NB) + wA0)        = pack8trunc(SA, SB);                     \
                *(uint4*)(lds + (NB) + wA0 + 8192) = pack8trunc(SC, SD);                     \
            } else if ((P) == 1) {                                                           \
                *(uint4*)(lds + (NB) + wA0 + 16384) = pack8trunc(SA, SB);                    \
                *(uint4*)(lds + (NB) + wA0 + 24576) = pack8trunc(SC, SD);                    \
            } else if ((P) == 2) {                                                           \
                *(uint4*)(lds + (NB) + 32768 + wB0)        = pack8trunc(SA, SB);             \
                *(uint4*)(lds + (NB) + 32768 + wB0 + 8192) = pack8trunc(SC, SD);             \
            } else {                                                                         \
                *(uint4*)(lds + (NB) + 49152 + wB0)        = pack8trunc(SA, SB);             \
                *(uint4*)(lds + (NB) + 49152 + wB0 + 8192) = pack8trunc(SC, SD);             \
            }                                                                                \
        }                                                                                    \
        {                                                                                    \
            const int TL = (T) + 1 + (((P) + 2) >> 2);                                       \
            if (TL < 16) {                                                                   \
                const unsigned int ko = (unsigned int)TL * 64u;                              \
                if ((((P) + 2) & 3) == 0) {                                                  \
                    SA = *(const float4*)(x + aoffs0 + ko); SB = *(const float4*)(x + aoffs0 + ko + 4); \
                    SC = *(const float4*)(x + aoffs1 + ko); SD = *(const float4*)(x + aoffs1 + ko + 4); \
                } else if ((((P) + 2) & 3) == 1) {                                           \
                    SA = *(const float4*)(x + aoffs2 + ko); SB = *(const float4*)(x + aoffs2 + ko + 4); \
                    SC = *(const float4*)(x + aoffs3 + ko); SD = *(const float4*)(x + aoffs3 + ko + 4); \
                } else if ((((P) + 2) & 3) == 2) {                                           \
                    SA = *(const float4*)(gbase + boff0 + ko); SB = *(const float4*)(gbase + boff0 + ko + 4); \
                    SC = *(const float4*)(gbase + boff1 + ko); SD = *(const float4*)(gbase + boff1 + ko + 4); \
                } else {                                                                     \
                    SA = *(const float4*)(ubase + boff0 + ko); SB = *(const float4*)(ubase + boff0 + ko + 4); \
                    SC = *(const float4*)(ubase + boff1 + ko); SD = *(const float4*)(ubase + boff1 + ko + 4); \
                }                                                                            \
            }                                                                                \
        }                                                                                    \
        bar_lgkm0();                                                                         \
        __builtin_amdgcn_s_setprio(1);                                                       \
        GU_MFMA16((P) >> 1, fa0, fa1, fa2, fa3)                                              \
        __builtin_amdgcn_s_setprio(0);                                                       \
        bar();                                                                               \
    }

    for (int t = 0; t < 16; ++t) {
        const unsigned int cb = (unsigned int)(t & 1) << 16;
        const unsigned int nb = cb ^ 65536u;
        GU_PHASE(t, 0, cb, nb, s0a, s0b, s0c, s0d)
        GU_PHASE(t, 1, cb, nb, s1a, s1b, s1c, s1d)
        GU_PHASE(t, 2, cb, nb, s0a, s0b, s0c, s0d)
        GU_PHASE(t, 3, cb, nb, s1a, s1b, s1c, s1d)
    }
#undef GU_PHASE
#undef GU_MFMA16

    const int hoff = offsets[e];
#pragma unroll
    for (int mf = 0; mf < 8; mf++)
#pragma unroll
        for (int v = 0; v < 4; v++) {
            int il = wm * 128 + mf * 16 + ((lane >> 4) << 2) + v;
            int i = mt * 256 + il;
            if (i < cnt) {
                size_t rowbase = (size_t)(hoff + i) * INTER + nt * 128 + wn * 32 + (lane & 15);
#pragma unroll
                for (int nf = 0; nf < 2; nf++) {
                    float g = accg[mf][nf][v], u = accu[mf][nf][v];
                    float sg = g / (1.f + __expf(-g));
                    h[rowbase + nf * 16] = f2bf(sg * u);
                }
            }
        }
}

// ---------------- K3: down grouped GEMM -> y (R9-verbatim) ----------------
__global__ __launch_bounds__(512) void gemm_down(
    const unsigned short* __restrict__ h, const float* __restrict__ dw,
    const int* __restrict__ counts, const int* __restrict__ offsets,
    const float* __restrict__ wts, float* __restrict__ y) {
    const int ez = blockIdx.z;                    // e*2 + ksp
    const int e = ez >> 1, ksp = ez & 1;
    const int cnt = counts[e];
    const int mt = blockIdx.y;
    if (mt * 128 >= cnt) return;
    const int nt = blockIdx.x;                    // 8 tiles of 128 hidden
    const int tid = threadIdx.x;
    const int lane = tid & 63, wid = tid >> 6;
    const int wm = wid >> 2, wn = wid & 3;        // 2x4 waves, wave 64x32

    __shared__ __align__(16) char lds[32768];     // [A 8K | B 8K] x2

    const int hoff = offsets[e];
    const float* dbase = dw + (size_t)e * HIDDEN * INTER;

    const int row = tid >> 2, kq = tid & 3;
    int li = mt * 128 + row; if (li >= cnt) li = cnt - 1;
    const unsigned int aoff = (unsigned int)((hoff + li) * INTER + ksp * 2048 + kq * 8);
    const unsigned int wAo = CHUNK(row, kq);
    const unsigned int boff = (unsigned int)((nt * 128 + row) * INTER + ksp * 2048 + kq * 8);
    const unsigned int wBo = 8192u + CHUNK(row, kq);

    f32x4 acc[4][2];
#pragma unroll
    for (int mf = 0; mf < 4; mf++)
#pragma unroll
        for (int nf = 0; nf < 2; nf++)
#pragma unroll
            for (int v = 0; v < 4; v++) acc[mf][nf][v] = 0.f;

    int4 av; float4 b0, b1;
    av = *(const int4*)(h + aoff);
    b0 = *(const float4*)(dbase + boff); b1 = *(const float4*)(dbase + boff + 4);

    for (int kt = 0; kt < 64; kt++) {             // 2048 K per split
        const unsigned int bb = (unsigned int)(kt & 1) << 14;
        *(int4*)(lds + bb + wAo) = av;
        *(uint4*)(lds + bb + wBo) = pack8trunc(b0, b1);
        if (kt < 63) {
            const int ko = (kt + 1) * 32;
            av = *(const int4*)(h + aoff + ko);
            b0 = *(const float4*)(dbase + boff + ko); b1 = *(const float4*)(dbase + boff + ko + 4);
        }
        block_sync();
        const unsigned int kqr = (unsigned int)(lane >> 4);
        const unsigned int rl = (unsigned int)(lane & 15);
        bf16x8 a[4];
#pragma unroll
        for (int mf = 0; mf < 4; mf++)
            a[mf] = *(const bf16x8*)(lds + bb + CHUNK(wm * 64 + mf * 16 + rl, kqr));
#pragma unroll
        for (int nf = 0; nf < 2; nf++) {
            bf16x8 b = *(const bf16x8*)(lds + bb + 8192 + CHUNK(wn * 32 + nf * 16 + rl, kqr));
#pragma unroll
            for (int mf = 0; mf < 4; mf++)
                acc[mf][nf] = __builtin_amdgcn_mfma_f32_16x16x32_bf16(a[mf], b, acc[mf][nf], 0, 0, 0);
        }
    }

#pragma unroll
    for (int mf = 0; mf < 4; mf++)
#pragma unroll
        for (int v = 0; v < 4; v++) {
            int il = wm * 64 + mf * 16 + ((lane >> 4) << 2) + v;
            int i = mt * 128 + il;
            if (i < cnt) {
                float w = wts[e * T_TOK + i];
                float* yrow = y + ((size_t)ksp * 4096 + hoff + i) * HIDDEN
                                + nt * 128 + wn * 32 + (lane & 15);
#pragma unroll
                for (int nf = 0; nf < 2; nf++)
                    yrow[nf * 16] = w * acc[mf][nf][v];
            }
        }
}

// -------- K4: combine (out[t] = sum over 2 experts x 2 ksplits) --------
__global__ __launch_bounds__(256) void combine_kernel(
    const float* __restrict__ y, const int* __restrict__ offsets,
    const int* __restrict__ tsel, float* __restrict__ out) {
    const int t = blockIdx.x;
    const int d = threadIdx.x * 4;
    int p0 = tsel[t * 2], p1 = tsel[t * 2 + 1];
    size_t g0 = (size_t)(offsets[p0 >> 11] + (p0 & (T_TOK - 1)));
    size_t g1 = (size_t)(offsets[p1 >> 11] + (p1 & (T_TOK - 1)));
    float4 a0 = *(const float4*)(y + g0 * HIDDEN + d);
    float4 a1 = *(const float4*)(y + (4096 + g0) * HIDDEN + d);
    float4 b0 = *(const float4*)(y + g1 * HIDDEN + d);
    float4 b1 = *(const float4*)(y + (4096 + g1) * HIDDEN + d);
    float4 o;
    o.x = (a0.x + a1.x) + (b0.x + b1.x);
    o.y = (a0.y + a1.y) + (b0.y + b1.y);
    o.z = (a0.z + a1.z) + (b0.z + b1.z);
    o.w = (a0.w + a1.w) + (b0.w + b1.w);
    *(float4*)(out + (size_t)t * HIDDEN + d) = o;
}

extern "C" void kernel_launch(void* const* d_in, const int* in_sizes, int n_in,
                              void* d_out, int out_size, void* d_ws, size_t ws_size,
                              hipStream_t stream) {
    const float* x  = (const float*)d_in[0];
    const float* rw = (const float*)d_in[1];
    const float* gw = (const float*)d_in[2];
    const float* uw = (const float*)d_in[3];
    const float* dw = (const float*)d_in[4];
    float* out = (float*)d_out;
    float* logits = out + (size_t)T_TOK * HIDDEN;

    char* ws = (char*)d_ws;
    int*   counts  = (int*)ws;                         // 32 B
    int*   offsets = (int*)(ws + 32);                  // 32 B
    int*   tsel    = (int*)(ws + 1024);                // 16 KB
    int*   ids     = (int*)(ws + 20480);               // 64 KB
    float* wts     = (float*)(ws + 90112);             // 64 KB
    unsigned short* h = (unsigned short*)(ws + 262144);        // 33.55 MB
    float* y       = (float*)(ws + 262144 + 33554432);         // 2 x 16.78 MB

    hipMemsetAsync(counts, 0, 8 * sizeof(int), stream);

    router_kernel<<<T_TOK / 4, 256, 0, stream>>>(x, rw, logits, counts, ids, wts, tsel);
    scan_kernel<<<1, 64, 0, stream>>>(counts, offsets);
    gemm_gu<<<dim3(INTER / 128, 8, NEXP), 512, 0, stream>>>(x, gw, uw, counts, offsets, ids, h);
    gemm_down<<<dim3(HIDDEN / 128, 16, NEXP * 2), 512, 0, stream>>>(h, dw, counts, offsets, wts, y);
    combine_kernel<<<T_TOK, 256, 0, stream>>>(y, offsets, tsel, out);
}